// Round 6
// baseline (140.044 us; speedup 1.0000x reference)
//
#include <hip/hip_runtime.h>

typedef _Float16 half8 __attribute__((ext_vector_type(8)));
typedef _Float16 half4 __attribute__((ext_vector_type(4)));
typedef float floatx4 __attribute__((ext_vector_type(4)));

static constexpr int NB  = 32;    // batches
static constexpr int NP  = 4096;  // points per batch
static constexpr int DD  = 128;   // dim
static constexpr int KC  = 64;    // clusters
static constexpr int TN  = 64;    // points per tile
static constexpr int TPB = 2;     // tiles per block (2 -> 1024 blocks)
static constexpr int SLOTS = NP / (TPB * TN);   // 32 partial slots per batch
static constexpr int STP = 72;    // sxt / sat pitch (halfwords).  NOTE: stride
                                  // 36 dwords ≡ 4 (mod 32 banks) is what makes
                                  // the XOR-swizzled b128 reads 2-way-max; do
                                  // not "optimize" to 64.
static constexpr int CHP = 136;   // sch pitch (halfwords): 68 dwords ≡ 4 (mod
                                  // 32) -- same good residue as STP.

#define ALPHA_  100.0f
#define LOG2E_  1.44269504088896f

// Workgroup barrier that waits ONLY on LDS (lgkmcnt), leaving prefetched
// global loads in flight. __syncthreads() would emit s_waitcnt vmcnt(0)
// and drain the prefetch on the critical path.
#define LGKM_BARRIER() asm volatile("s_waitcnt lgkmcnt(0)\ns_barrier" ::: "memory")

// Kernel 1: distances -> softmax -> block-private vlad partial.
// Register history: with centroid frags held in registers (chi[4][4] = 64
// VGPRs) unified demand was ~184 -> (256,3)'s 160-cap spilled ~60 MB/dispatch
// (round 3), (256,4) spilled ~270 MB (round 2).  Centroids live in LDS (sch,
// 17 KB, swizzled) so demand is ~140: (256,3) fits spill-free -> 3 blocks/CU.
// Do NOT move chi back to registers and do NOT raise min-waves.
// Partials are stored fp16: rounding adds ~1e-5 post-normalization error,
// two orders below the harness's 4.88e-4 bf16-compare floor, and halves the
// vp round-trip (33.5 -> 16.8 MB each way).
__global__ __launch_bounds__(256, 3)
void vlad_main(const float* __restrict__ xg, const float* __restrict__ cg,
               _Float16* __restrict__ vp, float* __restrict__ cpart)
{
    __shared__ __align__(16) _Float16 sxt[DD][STP];  // x^T [d][n^swz]
    __shared__ __align__(16) _Float16 sat[KC][STP];  // a^T [k][n^swz]
    __shared__ __align__(16) _Float16 sch[KC][CHP];  // centroids [k][d^swz]
    __shared__ float sc2[KC];

    const int tid  = threadIdx.x;
    const int lane = tid & 63;
    const int w    = tid >> 6;
    const int l15  = lane & 15;
    const int quad = lane >> 4;
    const int b    = blockIdx.y;
    const int s    = blockIdx.x;          // slot within batch
    const float* xb = xg + (size_t)b * NP * DD;

    const int nloc = w*16 + l15;
    const int scol = nloc ^ (quad << 4);
    const float* xpt = xb + (size_t)(s*TPB*TN + nloc)*DD + quad*8;

    // ---- issue x tile-0 loads FIRST (cold HBM; hide under centroid prep) ----
    float4 fa[4], fb[4];
#pragma unroll
    for (int ks = 0; ks < 4; ++ks) {
        fa[ks] = *(const float4*)(xpt + ks*32);
        fb[ks] = *(const float4*)(xpt + ks*32 + 4);
    }

    // ---- stage centroids -> LDS fp16 (swizzled like sxt) + exact fp32 c2.
    // Cooperative: thread t handles row t>>2, 32 columns (t&3)*32. ----
    {
        const int crow = tid >> 2;          // 0..63
        const int cc0  = (tid & 3) * 32;    // column base
        const int csw  = ((crow >> 3) & 1) << 4;
        const float* cp = cg + crow*DD + cc0;
        float c2part = 0.f;
#pragma unroll
        for (int j = 0; j < 4; ++j) {
            float4 a  = *(const float4*)(cp + j*8);
            float4 bb = *(const float4*)(cp + j*8 + 4);
            half8 h;
            h[0]=(_Float16)a.x;  h[1]=(_Float16)a.y;  h[2]=(_Float16)a.z;  h[3]=(_Float16)a.w;
            h[4]=(_Float16)bb.x; h[5]=(_Float16)bb.y; h[6]=(_Float16)bb.z; h[7]=(_Float16)bb.w;
            *(half8*)&sch[crow][(cc0 + j*8) ^ csw] = h;
            c2part += a.x*a.x + a.y*a.y + a.z*a.z + a.w*a.w
                    + bb.x*bb.x + bb.y*bb.y + bb.z*bb.z + bb.w*bb.w;
        }
        // 4 threads (same wave) share a row: pairwise reduce, lane t&3==0 writes
        c2part += __shfl_xor(c2part, 1);
        c2part += __shfl_xor(c2part, 2);
        if ((tid & 3) == 0) sc2[crow] = c2part;
    }
    LGKM_BARRIER();   // sch/sc2 ready (x tile-0 loads stay in flight)

    floatx4 acc2[8];   // vlad partial: row k = w*16+quad*4+r, col d = nt*16+l15
#pragma unroll
    for (int i = 0; i < 8; ++i) acc2[i] = (floatx4){0.f, 0.f, 0.f, 0.f};
    floatx4 accs = (floatx4){0.f, 0.f, 0.f, 0.f};  // colsum via ones-column MFMA

    half8 onesf;       // B[point][col] = (col==0)
#pragma unroll
    for (int j = 0; j < 8; ++j) onesf[j] = (_Float16)((l15 == 0) ? 1.0f : 0.0f);

    const int cswr = ((l15 >> 3) & 1) << 4;   // sch read swizzle (row bit 3)

#pragma unroll
    for (int tt = 0; tt < TPB; ++tt) {
        // ---- convert staged fp32 -> fp16 frags; per-lane ssq ----
        half8 xf[4];
        float ssq = 0.f;
#pragma unroll
        for (int ks = 0; ks < 4; ++ks) {
            half8 h;
            h[0]=(_Float16)fa[ks].x; h[1]=(_Float16)fa[ks].y;
            h[2]=(_Float16)fa[ks].z; h[3]=(_Float16)fa[ks].w;
            h[4]=(_Float16)fb[ks].x; h[5]=(_Float16)fb[ks].y;
            h[6]=(_Float16)fb[ks].z; h[7]=(_Float16)fb[ks].w;
            xf[ks] = h;
            ssq += fa[ks].x*fa[ks].x + fa[ks].y*fa[ks].y + fa[ks].z*fa[ks].z + fa[ks].w*fa[ks].w
                 + fb[ks].x*fb[ks].x + fb[ks].y*fb[ks].y + fb[ks].z*fb[ks].z + fb[ks].w*fb[ks].w;
        }

        // ---- prefetch next tile; stays in flight across the lgkm barrier ----
        if (tt + 1 < TPB) {
            const float* xr = xpt + (size_t)(tt + 1) * TN * DD;
#pragma unroll
            for (int ks = 0; ks < 4; ++ks) {
                fa[ks] = *(const float4*)(xr + ks*32);
                fb[ks] = *(const float4*)(xr + ks*32 + 4);
            }
        }

        // ---- write x^T (swizzled; 2-way max = free).  Safe: previous tile's
        // readers all passed the end-of-iteration barrier. ----
#pragma unroll
        for (int ks = 0; ks < 4; ++ks)
#pragma unroll
            for (int j = 0; j < 8; ++j)
                sxt[ks*32 + quad*8 + j][scol] = xf[ks][j];

        // ---- GEMM1: S^T[cluster][point]; A-frags streamed from sch ----
        floatx4 acc1[4];
#pragma unroll
        for (int mt = 0; mt < 4; ++mt) acc1[mt] = (floatx4){0.f, 0.f, 0.f, 0.f};
#pragma unroll
        for (int ks = 0; ks < 4; ++ks)
#pragma unroll
            for (int mt = 0; mt < 4; ++mt) {
                half8 cf = *(const half8*)&sch[mt*16 + l15][(ks*32 + quad*8) ^ cswr];
                acc1[mt] = __builtin_amdgcn_mfma_f32_16x16x32_f16(cf, xf[ks], acc1[mt], 0, 0, 0);
            }
        ssq += __shfl_xor(ssq, 16);
        ssq += __shfl_xor(ssq, 32);

        // ---- softmax over 64 clusters for this lane's point ----
        float dist[4][4];
#pragma unroll
        for (int mt = 0; mt < 4; ++mt) {
            floatx4 c2v = *(const floatx4*)&sc2[mt*16 + quad*4];
#pragma unroll
            for (int r = 0; r < 4; ++r) {
                float d2 = ssq + c2v[r] - 2.f*acc1[mt][r];
                dist[mt][r] = sqrtf(fmaxf(d2, 0.f));
            }
        }
        float dmin = dist[0][0];
#pragma unroll
        for (int mt = 0; mt < 4; ++mt)
#pragma unroll
            for (int r = 0; r < 4; ++r) dmin = fminf(dmin, dist[mt][r]);
        dmin = fminf(dmin, __shfl_xor(dmin, 16));
        dmin = fminf(dmin, __shfl_xor(dmin, 32));
        float pv[4][4];
        float psum = 0.f;
#pragma unroll
        for (int mt = 0; mt < 4; ++mt)
#pragma unroll
            for (int r = 0; r < 4; ++r) {
                float e = exp2f((dmin - dist[mt][r]) * (ALPHA_ * LOG2E_));
                pv[mt][r] = e; psum += e;
            }
        psum += __shfl_xor(psum, 16);
        psum += __shfl_xor(psum, 32);
        float invs = 1.0f / psum;
#pragma unroll
        for (int mt = 0; mt < 4; ++mt)
#pragma unroll
            for (int r = 0; r < 4; ++r)
                sat[mt*16 + quad*4 + r][scol] = (_Float16)(pv[mt][r] * invs);

        LGKM_BARRIER();   // sxt/sat visible; prefetch loads NOT drained

        // ---- GEMM2: vlad[k][d] += a^T · x ; colsum via ones column ----
#pragma unroll
        for (int ks2 = 0; ks2 < 2; ++ks2) {
            const int nbase = ks2*32 + quad*8;
            half8 af = *(const half8*)&sat[w*16 + l15][nbase ^ ((l15 >> 2) << 4)];
            accs = __builtin_amdgcn_mfma_f32_16x16x32_f16(af, onesf, accs, 0, 0, 0);
#pragma unroll
            for (int nt = 0; nt < 8; ++nt) {
                const int d = nt*16 + l15;
                half8 bf = *(const half8*)&sxt[d][nbase ^ (((d >> 3) & 3) << 4)];
                acc2[nt] = __builtin_amdgcn_mfma_f32_16x16x32_f16(af, bf, acc2[nt], 0, 0, 0);
            }
        }

        // reads of this tile done before next tile's writes (skip on last)
        if (tt + 1 < TPB) LGKM_BARRIER();
    }

    // ---- epilogue: fp16 stores into this block's private slot (coalesced
    // 2B/lane segments; same instruction count as fp32, half the bytes) ----
    _Float16* slot = vp + ((size_t)b*SLOTS + s) * (KC*DD);
#pragma unroll
    for (int nt = 0; nt < 8; ++nt)
#pragma unroll
        for (int r = 0; r < 4; ++r) {
            int k = w*16 + quad*4 + r;
            int d = nt*16 + l15;
            slot[k*DD + d] = (_Float16)acc2[nt][r];
        }
    if (l15 == 0) {
#pragma unroll
        for (int r = 0; r < 4; ++r)
            cpart[((size_t)b*SLOTS + s)*KC + w*16 + quad*4 + r] = accs[r];
    }
}

// Kernel 2 (fused): reduce fp16 partials (8 blocks/batch), subtract colsum*c,
// write reduced vlad + per-chunk ssq; the LAST block of each batch (per-batch
// atomic counter) then normalizes the whole batch and writes `out`.
// Cross-XCD visibility: writers do stores -> per-thread __threadfence()
// (agent release, L2 writeback on non-coherent XCDs) -> __syncthreads ->
// tid0 atomicAdd.  The last block re-fences (acquire/invalidate) before
// reading sibling chunks.  Values are deterministic (order-independent sums).
__global__ __launch_bounds__(256)
void vlad_reduce_norm(const _Float16* __restrict__ vp, const float* __restrict__ cpart,
                      const float* __restrict__ cg, float* __restrict__ vfull,
                      float* __restrict__ ssp, float* __restrict__ out,
                      unsigned* __restrict__ cnt)
{
    __shared__ float scs[KC];
    __shared__ float red[4];
    __shared__ int slast;
    const int b   = blockIdx.x >> 3;
    const int q   = blockIdx.x & 7;       // 1024-element chunk
    const int tid = threadIdx.x;

    if (tid < KC) {
        float cs = 0.f;
#pragma unroll
        for (int si = 0; si < SLOTS; ++si)
            cs += cpart[((size_t)b*SLOTS + si)*KC + tid];
        scs[tid] = cs;
    }
    __syncthreads();

    const int idx = q*1024 + tid*4;       // 4 consecutive elements per thread
    const _Float16* vpb = vp + (size_t)b*SLOTS*(KC*DD) + idx;
    float4 a = {0.f, 0.f, 0.f, 0.f};
#pragma unroll
    for (int si = 0; si < SLOTS; ++si) {
        half4 t = *(const half4*)(vpb + (size_t)si*(KC*DD));   // 8B coalesced
        a.x += (float)t[0]; a.y += (float)t[1];
        a.z += (float)t[2]; a.w += (float)t[3];
    }
    float cs = scs[idx >> 7];             // same cluster for all 4 (128 | idx)
    float4 cv = *(const float4*)(cg + idx);
    a.x -= cs*cv.x; a.y -= cs*cv.y; a.z -= cs*cv.z; a.w -= cs*cv.w;
    *(float4*)(vfull + (size_t)b*(KC*DD) + idx) = a;
    float ss = a.x*a.x + a.y*a.y + a.z*a.z + a.w*a.w;
#pragma unroll
    for (int m = 1; m < 64; m <<= 1) ss += __shfl_xor(ss, m);
    if ((tid & 63) == 0) red[tid >> 6] = ss;
    __syncthreads();
    if (tid == 0) ssp[b*8 + q] = red[0] + red[1] + red[2] + red[3];

    // ---- release: chunk + ssp visible device-wide, then bump counter ----
    __threadfence();
    __syncthreads();
    if (tid == 0) {
        unsigned old = atomicAdd(&cnt[b], 1u);
        slast = (old == 7u);
    }
    __syncthreads();
    if (!slast) return;

    // ---- last block for batch b: acquire, then normalize whole batch ----
    __threadfence();
    float tot = 0.f;
#pragma unroll
    for (int qq = 0; qq < 8; ++qq) tot += ssp[b*8 + qq];
    float scale = 1.0f / fmaxf(sqrtf(tot), 1e-12f);
#pragma unroll
    for (int i = 0; i < 8; ++i) {
        const int ix = i*1024 + tid*4;
        float4 v = *(const float4*)(vfull + (size_t)b*(KC*DD) + ix);
        v.x *= scale; v.y *= scale; v.z *= scale; v.w *= scale;
        *(float4*)(out + (size_t)b*(KC*DD) + ix) = v;
    }
}

extern "C" void kernel_launch(void* const* d_in, const int* in_sizes, int n_in,
                              void* d_out, int out_size, void* d_ws, size_t ws_size,
                              hipStream_t stream)
{
    (void)in_sizes; (void)n_in; (void)out_size; (void)ws_size;
    const float* x = (const float*)d_in[0];
    const float* c = (const float*)d_in[1];
    float* out     = (float*)d_out;
    _Float16* vp   = (_Float16*)d_ws;                        // [32][32][64][128] fp16 = 16.8 MB
    float* cpart = (float*)(vp + (size_t)NB*SLOTS*KC*DD);    // [32][32][64] fp32
    float* vfull = cpart + (size_t)NB*SLOTS*KC;              // [32][8192]
    float* ssp   = vfull + (size_t)NB*KC*DD;                 // [32][8]
    unsigned* cnt = (unsigned*)(ssp + (size_t)NB*8);         // [32]

    // zero the per-batch completion counters (128 B, graph-capturable node)
    hipMemsetAsync(cnt, 0, NB*sizeof(unsigned), stream);

    vlad_main<<<dim3(SLOTS, NB), 256, 0, stream>>>(x, c, vp, cpart);
    vlad_reduce_norm<<<NB*8, 256, 0, stream>>>(vp, cpart, c, vfull, ssp, out, cnt);
}

// Round 7
// 118.850 us; speedup vs baseline: 1.1783x; 1.1783x over previous
//
#include <hip/hip_runtime.h>

typedef _Float16 half8 __attribute__((ext_vector_type(8)));
typedef _Float16 half4 __attribute__((ext_vector_type(4)));
typedef float floatx4 __attribute__((ext_vector_type(4)));

static constexpr int NB  = 32;    // batches
static constexpr int NP  = 4096;  // points per batch
static constexpr int DD  = 128;   // dim
static constexpr int KC  = 64;    // clusters
static constexpr int TN  = 64;    // points per tile
// Balanced grid: 64 tiles/batch split over 24 slots: slots 0..15 take 3
// tiles, slots 16..23 take 2 (16*3 + 8*2 = 64).  24 slots * 32 batches =
// 768 blocks = EXACTLY 3 blocks/CU (the register-bound occupancy) -- no
// scheduling remainder, 25% fewer block prologues than the 1024-block grid,
// and vp shrinks 16.8 -> 12.6 MB.
static constexpr int SLOTS = 24;
static constexpr int STP = 72;    // sxt / sat pitch (halfwords).  NOTE: stride
                                  // 36 dwords ≡ 4 (mod 32 banks) is what makes
                                  // the XOR-swizzled b128 reads 2-way-max; do
                                  // not "optimize" to 64.
static constexpr int CHP = 136;   // sch pitch (halfwords): 68 dwords ≡ 4 (mod
                                  // 32) -- same good residue as STP.

#define ALPHA_  100.0f
#define LOG2E_  1.44269504088896f

// Workgroup barrier that waits ONLY on LDS (lgkmcnt), leaving prefetched
// global loads in flight. __syncthreads() would emit s_waitcnt vmcnt(0)
// and drain the prefetch on the critical path.
#define LGKM_BARRIER() asm volatile("s_waitcnt lgkmcnt(0)\ns_barrier" ::: "memory")

// Kernel 1: distances -> softmax -> block-private vlad partial.
// Register history: with centroid frags held in registers (chi[4][4] = 64
// VGPRs) unified demand was ~184 -> (256,3)'s 160-cap spilled ~60 MB/dispatch
// (round 3), (256,4) spilled ~270 MB (round 2).  Centroids live in LDS (sch,
// 17 KB, swizzled) so demand is ~140: (256,3) fits spill-free -> 3 blocks/CU.
// Do NOT move chi back to registers and do NOT raise min-waves.
// Partials are stored fp16: rounding adds ~1e-5 post-normalization error,
// two orders below the harness's 4.88e-4 bf16-compare floor.
// Round-6 lesson: do NOT fuse the reduction in via __threadfence/last-block --
// device-scope fences are an L2 writeback on gfx950 and cost ~35 us across
// the grid.  Keep the plain 3-kernel pipeline.
__global__ __launch_bounds__(256, 3)
void vlad_main(const float* __restrict__ xg, const float* __restrict__ cg,
               _Float16* __restrict__ vp, float* __restrict__ cpart)
{
    __shared__ __align__(16) _Float16 sxt[DD][STP];  // x^T [d][n^swz]
    __shared__ __align__(16) _Float16 sat[KC][STP];  // a^T [k][n^swz]
    __shared__ __align__(16) _Float16 sch[KC][CHP];  // centroids [k][d^swz]
    __shared__ float sc2[KC];

    const int tid  = threadIdx.x;
    const int lane = tid & 63;
    const int w    = tid >> 6;
    const int l15  = lane & 15;
    const int quad = lane >> 4;
    const int b    = blockIdx.y;
    const int s    = blockIdx.x;          // slot within batch (0..23)
    // slot -> tile range (block-uniform; barriers below stay convergent)
    const int t0  = (s < 16) ? 3*s : 48 + 2*(s - 16);
    const int ntl = (s < 16) ? 3 : 2;
    const float* xb = xg + (size_t)b * NP * DD;

    const int nloc = w*16 + l15;
    const int scol = nloc ^ (quad << 4);
    const float* xpt = xb + (size_t)(t0*TN + nloc)*DD + quad*8;

    // ---- issue x tile-0 loads FIRST (cold HBM; hide under centroid prep) ----
    float4 fa[4], fb[4];
#pragma unroll
    for (int ks = 0; ks < 4; ++ks) {
        fa[ks] = *(const float4*)(xpt + ks*32);
        fb[ks] = *(const float4*)(xpt + ks*32 + 4);
    }

    // ---- stage centroids -> LDS fp16 (swizzled like sxt) + exact fp32 c2.
    // Cooperative: thread t handles row t>>2, 32 columns (t&3)*32. ----
    {
        const int crow = tid >> 2;          // 0..63
        const int cc0  = (tid & 3) * 32;    // column base
        const int csw  = ((crow >> 3) & 1) << 4;
        const float* cp = cg + crow*DD + cc0;
        float c2part = 0.f;
#pragma unroll
        for (int j = 0; j < 4; ++j) {
            float4 a  = *(const float4*)(cp + j*8);
            float4 bb = *(const float4*)(cp + j*8 + 4);
            half8 h;
            h[0]=(_Float16)a.x;  h[1]=(_Float16)a.y;  h[2]=(_Float16)a.z;  h[3]=(_Float16)a.w;
            h[4]=(_Float16)bb.x; h[5]=(_Float16)bb.y; h[6]=(_Float16)bb.z; h[7]=(_Float16)bb.w;
            *(half8*)&sch[crow][(cc0 + j*8) ^ csw] = h;
            c2part += a.x*a.x + a.y*a.y + a.z*a.z + a.w*a.w
                    + bb.x*bb.x + bb.y*bb.y + bb.z*bb.z + bb.w*bb.w;
        }
        // 4 threads (same wave) share a row: pairwise reduce, lane t&3==0 writes
        c2part += __shfl_xor(c2part, 1);
        c2part += __shfl_xor(c2part, 2);
        if ((tid & 3) == 0) sc2[crow] = c2part;
    }
    LGKM_BARRIER();   // sch/sc2 ready (x tile-0 loads stay in flight)

    floatx4 acc2[8];   // vlad partial: row k = w*16+quad*4+r, col d = nt*16+l15
#pragma unroll
    for (int i = 0; i < 8; ++i) acc2[i] = (floatx4){0.f, 0.f, 0.f, 0.f};
    floatx4 accs = (floatx4){0.f, 0.f, 0.f, 0.f};  // colsum via ones-column MFMA

    half8 onesf;       // B[point][col] = (col==0)
#pragma unroll
    for (int j = 0; j < 8; ++j) onesf[j] = (_Float16)((l15 == 0) ? 1.0f : 0.0f);

    const int cswr = ((l15 >> 3) & 1) << 4;   // sch read swizzle (row bit 3)

    for (int tt = 0; tt < ntl; ++tt) {
        // ---- convert staged fp32 -> fp16 frags; per-lane ssq ----
        half8 xf[4];
        float ssq = 0.f;
#pragma unroll
        for (int ks = 0; ks < 4; ++ks) {
            half8 h;
            h[0]=(_Float16)fa[ks].x; h[1]=(_Float16)fa[ks].y;
            h[2]=(_Float16)fa[ks].z; h[3]=(_Float16)fa[ks].w;
            h[4]=(_Float16)fb[ks].x; h[5]=(_Float16)fb[ks].y;
            h[6]=(_Float16)fb[ks].z; h[7]=(_Float16)fb[ks].w;
            xf[ks] = h;
            ssq += fa[ks].x*fa[ks].x + fa[ks].y*fa[ks].y + fa[ks].z*fa[ks].z + fa[ks].w*fa[ks].w
                 + fb[ks].x*fb[ks].x + fb[ks].y*fb[ks].y + fb[ks].z*fb[ks].z + fb[ks].w*fb[ks].w;
        }

        // ---- prefetch next tile; stays in flight across the lgkm barrier ----
        if (tt + 1 < ntl) {
            const float* xr = xpt + (size_t)(tt + 1) * TN * DD;
#pragma unroll
            for (int ks = 0; ks < 4; ++ks) {
                fa[ks] = *(const float4*)(xr + ks*32);
                fb[ks] = *(const float4*)(xr + ks*32 + 4);
            }
        }

        // ---- write x^T (swizzled; 2-way max = free).  Safe: previous tile's
        // readers all passed the end-of-iteration barrier. ----
#pragma unroll
        for (int ks = 0; ks < 4; ++ks)
#pragma unroll
            for (int j = 0; j < 8; ++j)
                sxt[ks*32 + quad*8 + j][scol] = xf[ks][j];

        // ---- GEMM1: S^T[cluster][point]; A-frags streamed from sch ----
        floatx4 acc1[4];
#pragma unroll
        for (int mt = 0; mt < 4; ++mt) acc1[mt] = (floatx4){0.f, 0.f, 0.f, 0.f};
#pragma unroll
        for (int ks = 0; ks < 4; ++ks)
#pragma unroll
            for (int mt = 0; mt < 4; ++mt) {
                half8 cf = *(const half8*)&sch[mt*16 + l15][(ks*32 + quad*8) ^ cswr];
                acc1[mt] = __builtin_amdgcn_mfma_f32_16x16x32_f16(cf, xf[ks], acc1[mt], 0, 0, 0);
            }
        ssq += __shfl_xor(ssq, 16);
        ssq += __shfl_xor(ssq, 32);

        // ---- softmax over 64 clusters for this lane's point ----
        float dist[4][4];
#pragma unroll
        for (int mt = 0; mt < 4; ++mt) {
            floatx4 c2v = *(const floatx4*)&sc2[mt*16 + quad*4];
#pragma unroll
            for (int r = 0; r < 4; ++r) {
                float d2 = ssq + c2v[r] - 2.f*acc1[mt][r];
                dist[mt][r] = sqrtf(fmaxf(d2, 0.f));
            }
        }
        float dmin = dist[0][0];
#pragma unroll
        for (int mt = 0; mt < 4; ++mt)
#pragma unroll
            for (int r = 0; r < 4; ++r) dmin = fminf(dmin, dist[mt][r]);
        dmin = fminf(dmin, __shfl_xor(dmin, 16));
        dmin = fminf(dmin, __shfl_xor(dmin, 32));
        float pv[4][4];
        float psum = 0.f;
#pragma unroll
        for (int mt = 0; mt < 4; ++mt)
#pragma unroll
            for (int r = 0; r < 4; ++r) {
                float e = exp2f((dmin - dist[mt][r]) * (ALPHA_ * LOG2E_));
                pv[mt][r] = e; psum += e;
            }
        psum += __shfl_xor(psum, 16);
        psum += __shfl_xor(psum, 32);
        float invs = 1.0f / psum;
#pragma unroll
        for (int mt = 0; mt < 4; ++mt)
#pragma unroll
            for (int r = 0; r < 4; ++r)
                sat[mt*16 + quad*4 + r][scol] = (_Float16)(pv[mt][r] * invs);

        LGKM_BARRIER();   // sxt/sat visible; prefetch loads NOT drained

        // ---- GEMM2: vlad[k][d] += a^T · x ; colsum via ones column ----
#pragma unroll
        for (int ks2 = 0; ks2 < 2; ++ks2) {
            const int nbase = ks2*32 + quad*8;
            half8 af = *(const half8*)&sat[w*16 + l15][nbase ^ ((l15 >> 2) << 4)];
            accs = __builtin_amdgcn_mfma_f32_16x16x32_f16(af, onesf, accs, 0, 0, 0);
#pragma unroll
            for (int nt = 0; nt < 8; ++nt) {
                const int d = nt*16 + l15;
                half8 bf = *(const half8*)&sxt[d][nbase ^ (((d >> 3) & 3) << 4)];
                acc2[nt] = __builtin_amdgcn_mfma_f32_16x16x32_f16(af, bf, acc2[nt], 0, 0, 0);
            }
        }

        // reads of this tile done before next tile's writes (block-uniform
        // condition -> convergent barrier; skipped on the final tile)
        if (tt + 1 < ntl) LGKM_BARRIER();
    }

    // ---- epilogue: fp16 stores into this block's private slot (coalesced
    // 2B/lane segments; same instruction count as fp32, half the bytes) ----
    _Float16* slot = vp + ((size_t)b*SLOTS + s) * (KC*DD);
#pragma unroll
    for (int nt = 0; nt < 8; ++nt)
#pragma unroll
        for (int r = 0; r < 4; ++r) {
            int k = w*16 + quad*4 + r;
            int d = nt*16 + l15;
            slot[k*DD + d] = (_Float16)acc2[nt][r];
        }
    if (l15 == 0) {
#pragma unroll
        for (int r = 0; r < 4; ++r)
            cpart[((size_t)b*SLOTS + s)*KC + w*16 + quad*4 + r] = accs[r];
    }
}

// Kernel 2: reduce fp16 partials (8 blocks/batch), subtract colsum*c, write
// reduced vlad (fp32) + per-chunk sum-of-squares.
__global__ __launch_bounds__(256)
void vlad_reduce(const _Float16* __restrict__ vp, const float* __restrict__ cpart,
                 const float* __restrict__ cg, float* __restrict__ vfull,
                 float* __restrict__ ssp)
{
    __shared__ float scs[KC];
    __shared__ float red[4];
    const int b   = blockIdx.x >> 3;
    const int q   = blockIdx.x & 7;       // 1024-element chunk
    const int tid = threadIdx.x;

    if (tid < KC) {
        float cs = 0.f;
#pragma unroll
        for (int si = 0; si < SLOTS; ++si)
            cs += cpart[((size_t)b*SLOTS + si)*KC + tid];
        scs[tid] = cs;
    }
    __syncthreads();

    const int idx = q*1024 + tid*4;       // 4 consecutive elements per thread
    const _Float16* vpb = vp + (size_t)b*SLOTS*(KC*DD) + idx;
    float4 a = {0.f, 0.f, 0.f, 0.f};
#pragma unroll
    for (int si = 0; si < SLOTS; ++si) {
        half4 t = *(const half4*)(vpb + (size_t)si*(KC*DD));   // 8B coalesced
        a.x += (float)t[0]; a.y += (float)t[1];
        a.z += (float)t[2]; a.w += (float)t[3];
    }
    float cs = scs[idx >> 7];             // same cluster for all 4 (128 | idx)
    float4 cv = *(const float4*)(cg + idx);
    a.x -= cs*cv.x; a.y -= cs*cv.y; a.z -= cs*cv.z; a.w -= cs*cv.w;
    *(float4*)(vfull + (size_t)b*(KC*DD) + idx) = a;
    float ss = a.x*a.x + a.y*a.y + a.z*a.z + a.w*a.w;
#pragma unroll
    for (int m = 1; m < 64; m <<= 1) ss += __shfl_xor(ss, m);
    if ((tid & 63) == 0) red[tid >> 6] = ss;
    __syncthreads();
    if (tid == 0) ssp[b*8 + q] = red[0] + red[1] + red[2] + red[3];
}

// Kernel 3: L2-normalize per batch
__global__ __launch_bounds__(256)
void vlad_norm(const float* __restrict__ vfull, const float* __restrict__ ssp,
               float* __restrict__ out)
{
    const int b   = blockIdx.x;
    const int tid = threadIdx.x;
    float tot = 0.f;
#pragma unroll
    for (int q = 0; q < 8; ++q) tot += ssp[b*8 + q];
    float scale = 1.0f / fmaxf(sqrtf(tot), 1e-12f);
#pragma unroll
    for (int i = 0; i < 8; ++i) {
        int idx = i*1024 + tid*4;
        float4 v = *(const float4*)(vfull + (size_t)b*(KC*DD) + idx);
        v.x *= scale; v.y *= scale; v.z *= scale; v.w *= scale;
        *(float4*)(out + (size_t)b*(KC*DD) + idx) = v;
    }
}

extern "C" void kernel_launch(void* const* d_in, const int* in_sizes, int n_in,
                              void* d_out, int out_size, void* d_ws, size_t ws_size,
                              hipStream_t stream)
{
    (void)in_sizes; (void)n_in; (void)out_size; (void)ws_size;
    const float* x = (const float*)d_in[0];
    const float* c = (const float*)d_in[1];
    float* out     = (float*)d_out;
    _Float16* vp   = (_Float16*)d_ws;                        // [32][24][64][128] fp16 = 12.6 MB
    float* cpart = (float*)(vp + (size_t)NB*SLOTS*KC*DD);    // [32][24][64] fp32
    float* vfull = cpart + (size_t)NB*SLOTS*KC;              // [32][8192]
    float* ssp   = vfull + (size_t)NB*KC*DD;                 // [32][8]

    vlad_main<<<dim3(SLOTS, NB), 256, 0, stream>>>(x, c, vp, cpart);
    vlad_reduce<<<NB*8, 256, 0, stream>>>(vp, cpart, c, vfull, ssp);
    vlad_norm<<<NB, 256, 0, stream>>>(vfull, ssp, out);
}

// Round 8
// 111.500 us; speedup vs baseline: 1.2560x; 1.0659x over previous
//
#include <hip/hip_runtime.h>

typedef _Float16 half8 __attribute__((ext_vector_type(8)));
typedef _Float16 half4 __attribute__((ext_vector_type(4)));
typedef float floatx4 __attribute__((ext_vector_type(4)));

static constexpr int NB  = 32;    // batches
static constexpr int NP  = 4096;  // points per batch
static constexpr int DD  = 128;   // dim
static constexpr int KC  = 64;    // clusters
static constexpr int TN  = 64;    // points per tile
static constexpr int TPB = 2;     // tiles per block -> 1024 blocks, UNIFORM.
                                  // Round-7 lesson: oversubscribed uniform
                                  // grids beat exactly-resident uneven ones
                                  // (24-slot 3/2-tile split cost +8 us).
static constexpr int SLOTS = NP / (TPB * TN);   // 32 partial slots per batch
static constexpr int STP = 72;    // sxt / sat pitch (halfwords).  NOTE: stride
                                  // 36 dwords ≡ 4 (mod 32 banks) is what makes
                                  // the XOR-swizzled b128 reads 2-way-max; do
                                  // not "optimize" to 64.
static constexpr int CHP = 136;   // sch pitch (halfwords): 68 dwords ≡ 4 (mod
                                  // 32) -- same good residue as STP.

#define ALPHA_  100.0f
#define LOG2E_  1.44269504088896f

// Workgroup barrier that waits ONLY on LDS (lgkmcnt), leaving prefetched
// global loads in flight. __syncthreads() would emit s_waitcnt vmcnt(0)
// and drain the prefetch on the critical path.
#define LGKM_BARRIER() asm volatile("s_waitcnt lgkmcnt(0)\ns_barrier" ::: "memory")

// Kernel 1: distances -> softmax -> block-private vlad partial.
// Register history: chi[4][4] in regs -> demand ~184: (256,4) spilled 270 MB
// (R2), (256,3) spilled 60 MB (R3).  Centroids in LDS (R4) -> demand ~140,
// (256,3) spill-free at 3 blocks/CU (R5 = 111.0 us).  THIS version halves the
// x prefetch (ks01 of next tile only, 16 regs; ks23 demand-loaded per tile
// with ~200cy of convert/sxt/GEMM1 cover) to push peak liveness to ~115 and
// tries (256,4) = 4 blocks/CU.  Canary for spill: main WRITE_SIZE >> 17 MB.
// Round-6 lesson: no __threadfence-based fusion (L2 writeback ~35 us).
// Partials stored fp16: ~1e-5 post-norm error, far below the 4.88e-4 floor.
__global__ __launch_bounds__(256, 4)
void vlad_main(const float* __restrict__ xg, const float* __restrict__ cg,
               _Float16* __restrict__ vp, float* __restrict__ cpart)
{
    __shared__ __align__(16) _Float16 sxt[DD][STP];  // x^T [d][n^swz]
    __shared__ __align__(16) _Float16 sat[KC][STP];  // a^T [k][n^swz]
    __shared__ __align__(16) _Float16 sch[KC][CHP];  // centroids [k][d^swz]
    __shared__ float sc2[KC];

    const int tid  = threadIdx.x;
    const int lane = tid & 63;
    const int w    = tid >> 6;
    const int l15  = lane & 15;
    const int quad = lane >> 4;
    const int b    = blockIdx.y;
    const int s    = blockIdx.x;          // slot within batch
    const float* xb = xg + (size_t)b * NP * DD;

    const int nloc = w*16 + l15;
    const int scol = nloc ^ (quad << 4);
    const float* xpt = xb + (size_t)(s*TPB*TN + nloc)*DD + quad*8;

    // ---- issue FIRST-HALF x tile-0 loads (cold HBM; hide under c-prep) ----
    float4 pfa[2], pfb[2];                // ks=0,1 prefetch regs (16 VGPRs)
#pragma unroll
    for (int ks = 0; ks < 2; ++ks) {
        pfa[ks] = *(const float4*)(xpt + ks*32);
        pfb[ks] = *(const float4*)(xpt + ks*32 + 4);
    }

    // ---- stage centroids -> LDS fp16 (swizzled like sxt) + exact fp32 c2.
    // Cooperative: thread t handles row t>>2, 32 columns (t&3)*32. ----
    {
        const int crow = tid >> 2;          // 0..63
        const int cc0  = (tid & 3) * 32;    // column base
        const int csw  = ((crow >> 3) & 1) << 4;
        const float* cp = cg + crow*DD + cc0;
        float c2part = 0.f;
#pragma unroll
        for (int j = 0; j < 4; ++j) {
            float4 a  = *(const float4*)(cp + j*8);
            float4 bb = *(const float4*)(cp + j*8 + 4);
            half8 h;
            h[0]=(_Float16)a.x;  h[1]=(_Float16)a.y;  h[2]=(_Float16)a.z;  h[3]=(_Float16)a.w;
            h[4]=(_Float16)bb.x; h[5]=(_Float16)bb.y; h[6]=(_Float16)bb.z; h[7]=(_Float16)bb.w;
            *(half8*)&sch[crow][(cc0 + j*8) ^ csw] = h;
            c2part += a.x*a.x + a.y*a.y + a.z*a.z + a.w*a.w
                    + bb.x*bb.x + bb.y*bb.y + bb.z*bb.z + bb.w*bb.w;
        }
        // 4 threads (same wave) share a row: pairwise reduce, lane t&3==0 writes
        c2part += __shfl_xor(c2part, 1);
        c2part += __shfl_xor(c2part, 2);
        if ((tid & 3) == 0) sc2[crow] = c2part;
    }
    LGKM_BARRIER();   // sch/sc2 ready (x tile-0 loads stay in flight)

    floatx4 acc2[8];   // vlad partial: row k = w*16+quad*4+r, col d = nt*16+l15
#pragma unroll
    for (int i = 0; i < 8; ++i) acc2[i] = (floatx4){0.f, 0.f, 0.f, 0.f};
    floatx4 accs = (floatx4){0.f, 0.f, 0.f, 0.f};  // colsum via ones-column MFMA

    half8 onesf;       // B[point][col] = (col==0)
#pragma unroll
    for (int j = 0; j < 8; ++j) onesf[j] = (_Float16)((l15 == 0) ? 1.0f : 0.0f);

    const int cswr = ((l15 >> 3) & 1) << 4;   // sch read swizzle (row bit 3)

#pragma unroll
    for (int tt = 0; tt < TPB; ++tt) {
        const float* xcur = xpt + (size_t)tt * TN * DD;

        // ---- issue SECOND-HALF loads for THIS tile (ks=2,3).  Consumed
        // after first-half convert + sxt writes + 8 MFMAs (~200cy of cover;
        // the rest is hidden by 16 waves/CU TLP). ----
        float4 ca[2], cb[2];
#pragma unroll
        for (int ks = 0; ks < 2; ++ks) {
            ca[ks] = *(const float4*)(xcur + (ks+2)*32);
            cb[ks] = *(const float4*)(xcur + (ks+2)*32 + 4);
        }

        // ---- first half: convert, ssq, write sxt ----
        half8 xf[4];
        float ssq = 0.f;
#pragma unroll
        for (int ks = 0; ks < 2; ++ks) {
            half8 h;
            h[0]=(_Float16)pfa[ks].x; h[1]=(_Float16)pfa[ks].y;
            h[2]=(_Float16)pfa[ks].z; h[3]=(_Float16)pfa[ks].w;
            h[4]=(_Float16)pfb[ks].x; h[5]=(_Float16)pfb[ks].y;
            h[6]=(_Float16)pfb[ks].z; h[7]=(_Float16)pfb[ks].w;
            xf[ks] = h;
            ssq += pfa[ks].x*pfa[ks].x + pfa[ks].y*pfa[ks].y + pfa[ks].z*pfa[ks].z + pfa[ks].w*pfa[ks].w
                 + pfb[ks].x*pfb[ks].x + pfb[ks].y*pfb[ks].y + pfb[ks].z*pfb[ks].z + pfb[ks].w*pfb[ks].w;
        }
#pragma unroll
        for (int ks = 0; ks < 2; ++ks)
#pragma unroll
            for (int j = 0; j < 8; ++j)
                sxt[ks*32 + quad*8 + j][scol] = xf[ks][j];

        // ---- pf regs are free: prefetch first half of NEXT tile ----
        if (tt + 1 < TPB) {
            const float* xr = xpt + (size_t)(tt + 1) * TN * DD;
#pragma unroll
            for (int ks = 0; ks < 2; ++ks) {
                pfa[ks] = *(const float4*)(xr + ks*32);
                pfb[ks] = *(const float4*)(xr + ks*32 + 4);
            }
        }

        // ---- GEMM1 first half (8 MFMAs; also covers ca/cb latency) ----
        floatx4 acc1[4];
#pragma unroll
        for (int mt = 0; mt < 4; ++mt) acc1[mt] = (floatx4){0.f, 0.f, 0.f, 0.f};
#pragma unroll
        for (int ks = 0; ks < 2; ++ks)
#pragma unroll
            for (int mt = 0; mt < 4; ++mt) {
                half8 cf = *(const half8*)&sch[mt*16 + l15][(ks*32 + quad*8) ^ cswr];
                acc1[mt] = __builtin_amdgcn_mfma_f32_16x16x32_f16(cf, xf[ks], acc1[mt], 0, 0, 0);
            }

        // ---- second half: convert (waits on ca/cb), ssq, sxt, GEMM1 ----
#pragma unroll
        for (int ks = 0; ks < 2; ++ks) {
            half8 h;
            h[0]=(_Float16)ca[ks].x; h[1]=(_Float16)ca[ks].y;
            h[2]=(_Float16)ca[ks].z; h[3]=(_Float16)ca[ks].w;
            h[4]=(_Float16)cb[ks].x; h[5]=(_Float16)cb[ks].y;
            h[6]=(_Float16)cb[ks].z; h[7]=(_Float16)cb[ks].w;
            xf[ks+2] = h;
            ssq += ca[ks].x*ca[ks].x + ca[ks].y*ca[ks].y + ca[ks].z*ca[ks].z + ca[ks].w*ca[ks].w
                 + cb[ks].x*cb[ks].x + cb[ks].y*cb[ks].y + cb[ks].z*cb[ks].z + cb[ks].w*cb[ks].w;
        }
#pragma unroll
        for (int ks = 2; ks < 4; ++ks)
#pragma unroll
            for (int j = 0; j < 8; ++j)
                sxt[ks*32 + quad*8 + j][scol] = xf[ks][j];
#pragma unroll
        for (int ks = 2; ks < 4; ++ks)
#pragma unroll
            for (int mt = 0; mt < 4; ++mt) {
                half8 cf = *(const half8*)&sch[mt*16 + l15][(ks*32 + quad*8) ^ cswr];
                acc1[mt] = __builtin_amdgcn_mfma_f32_16x16x32_f16(cf, xf[ks], acc1[mt], 0, 0, 0);
            }
        ssq += __shfl_xor(ssq, 16);
        ssq += __shfl_xor(ssq, 32);

        // ---- softmax over 64 clusters for this lane's point ----
        float dist[4][4];
#pragma unroll
        for (int mt = 0; mt < 4; ++mt) {
            floatx4 c2v = *(const floatx4*)&sc2[mt*16 + quad*4];
#pragma unroll
            for (int r = 0; r < 4; ++r) {
                float d2 = ssq + c2v[r] - 2.f*acc1[mt][r];
                dist[mt][r] = sqrtf(fmaxf(d2, 0.f));
            }
        }
        float dmin = dist[0][0];
#pragma unroll
        for (int mt = 0; mt < 4; ++mt)
#pragma unroll
            for (int r = 0; r < 4; ++r) dmin = fminf(dmin, dist[mt][r]);
        dmin = fminf(dmin, __shfl_xor(dmin, 16));
        dmin = fminf(dmin, __shfl_xor(dmin, 32));
        float pv[4][4];
        float psum = 0.f;
#pragma unroll
        for (int mt = 0; mt < 4; ++mt)
#pragma unroll
            for (int r = 0; r < 4; ++r) {
                float e = exp2f((dmin - dist[mt][r]) * (ALPHA_ * LOG2E_));
                pv[mt][r] = e; psum += e;
            }
        psum += __shfl_xor(psum, 16);
        psum += __shfl_xor(psum, 32);
        float invs = 1.0f / psum;
#pragma unroll
        for (int mt = 0; mt < 4; ++mt)
#pragma unroll
            for (int r = 0; r < 4; ++r)
                sat[mt*16 + quad*4 + r][scol] = (_Float16)(pv[mt][r] * invs);

        LGKM_BARRIER();   // sxt/sat visible; prefetch loads NOT drained

        // ---- GEMM2: vlad[k][d] += a^T · x ; colsum via ones column ----
#pragma unroll
        for (int ks2 = 0; ks2 < 2; ++ks2) {
            const int nbase = ks2*32 + quad*8;
            half8 af = *(const half8*)&sat[w*16 + l15][nbase ^ ((l15 >> 2) << 4)];
            accs = __builtin_amdgcn_mfma_f32_16x16x32_f16(af, onesf, accs, 0, 0, 0);
#pragma unroll
            for (int nt = 0; nt < 8; ++nt) {
                const int d = nt*16 + l15;
                half8 bf = *(const half8*)&sxt[d][nbase ^ (((d >> 3) & 3) << 4)];
                acc2[nt] = __builtin_amdgcn_mfma_f32_16x16x32_f16(af, bf, acc2[nt], 0, 0, 0);
            }
        }

        // reads of this tile done before next tile's writes (skip on last)
        if (tt + 1 < TPB) LGKM_BARRIER();
    }

    // ---- epilogue: fp16 stores into this block's private slot (coalesced
    // 2B/lane segments; same instruction count as fp32, half the bytes) ----
    _Float16* slot = vp + ((size_t)b*SLOTS + s) * (KC*DD);
#pragma unroll
    for (int nt = 0; nt < 8; ++nt)
#pragma unroll
        for (int r = 0; r < 4; ++r) {
            int k = w*16 + quad*4 + r;
            int d = nt*16 + l15;
            slot[k*DD + d] = (_Float16)acc2[nt][r];
        }
    if (l15 == 0) {
#pragma unroll
        for (int r = 0; r < 4; ++r)
            cpart[((size_t)b*SLOTS + s)*KC + w*16 + quad*4 + r] = accs[r];
    }
}

// Kernel 2: reduce fp16 partials (8 blocks/batch), subtract colsum*c, write
// reduced vlad (fp32) + per-chunk sum-of-squares.
__global__ __launch_bounds__(256)
void vlad_reduce(const _Float16* __restrict__ vp, const float* __restrict__ cpart,
                 const float* __restrict__ cg, float* __restrict__ vfull,
                 float* __restrict__ ssp)
{
    __shared__ float scs[KC];
    __shared__ float red[4];
    const int b   = blockIdx.x >> 3;
    const int q   = blockIdx.x & 7;       // 1024-element chunk
    const int tid = threadIdx.x;

    if (tid < KC) {
        float cs = 0.f;
#pragma unroll
        for (int si = 0; si < SLOTS; ++si)
            cs += cpart[((size_t)b*SLOTS + si)*KC + tid];
        scs[tid] = cs;
    }
    __syncthreads();

    const int idx = q*1024 + tid*4;       // 4 consecutive elements per thread
    const _Float16* vpb = vp + (size_t)b*SLOTS*(KC*DD) + idx;
    float4 a = {0.f, 0.f, 0.f, 0.f};
#pragma unroll
    for (int si = 0; si < SLOTS; ++si) {
        half4 t = *(const half4*)(vpb + (size_t)si*(KC*DD));   // 8B coalesced
        a.x += (float)t[0]; a.y += (float)t[1];
        a.z += (float)t[2]; a.w += (float)t[3];
    }
    float cs = scs[idx >> 7];             // same cluster for all 4 (128 | idx)
    float4 cv = *(const float4*)(cg + idx);
    a.x -= cs*cv.x; a.y -= cs*cv.y; a.z -= cs*cv.z; a.w -= cs*cv.w;
    *(float4*)(vfull + (size_t)b*(KC*DD) + idx) = a;
    float ss = a.x*a.x + a.y*a.y + a.z*a.z + a.w*a.w;
#pragma unroll
    for (int m = 1; m < 64; m <<= 1) ss += __shfl_xor(ss, m);
    if ((tid & 63) == 0) red[tid >> 6] = ss;
    __syncthreads();
    if (tid == 0) ssp[b*8 + q] = red[0] + red[1] + red[2] + red[3];
}

// Kernel 3: L2-normalize per batch
__global__ __launch_bounds__(256)
void vlad_norm(const float* __restrict__ vfull, const float* __restrict__ ssp,
               float* __restrict__ out)
{
    const int b   = blockIdx.x;
    const int tid = threadIdx.x;
    float tot = 0.f;
#pragma unroll
    for (int q = 0; q < 8; ++q) tot += ssp[b*8 + q];
    float scale = 1.0f / fmaxf(sqrtf(tot), 1e-12f);
#pragma unroll
    for (int i = 0; i < 8; ++i) {
        int idx = i*1024 + tid*4;
        float4 v = *(const float4*)(vfull + (size_t)b*(KC*DD) + idx);
        v.x *= scale; v.y *= scale; v.z *= scale; v.w *= scale;
        *(float4*)(out + (size_t)b*(KC*DD) + idx) = v;
    }
}

extern "C" void kernel_launch(void* const* d_in, const int* in_sizes, int n_in,
                              void* d_out, int out_size, void* d_ws, size_t ws_size,
                              hipStream_t stream)
{
    (void)in_sizes; (void)n_in; (void)out_size; (void)ws_size;
    const float* x = (const float*)d_in[0];
    const float* c = (const float*)d_in[1];
    float* out     = (float*)d_out;
    _Float16* vp   = (_Float16*)d_ws;                        // [32][32][64][128] fp16 = 16.8 MB
    float* cpart = (float*)(vp + (size_t)NB*SLOTS*KC*DD);    // [32][32][64] fp32
    float* vfull = cpart + (size_t)NB*SLOTS*KC;              // [32][8192]
    float* ssp   = vfull + (size_t)NB*KC*DD;                 // [32][8]

    vlad_main<<<dim3(SLOTS, NB), 256, 0, stream>>>(x, c, vp, cpart);
    vlad_reduce<<<NB*8, 256, 0, stream>>>(vp, cpart, c, vfull, ssp);
    vlad_norm<<<NB, 256, 0, stream>>>(vfull, ssp, out);
}